// Round 5
// baseline (88.058 us; speedup 1.0000x reference)
//
#include <hip/hip_runtime.h>
#include <hip/hip_fp16.h>
#include <math.h>

typedef _Float16 f16;
typedef _Float16 f16x8 __attribute__((ext_vector_type(8)));
typedef _Float16 f16x4v __attribute__((ext_vector_type(4)));
typedef float f32x4 __attribute__((ext_vector_type(4)));

#define BATCH   2
#define LSEQ    1024
#define BLTOT   2048
#define DMODEL  512
#define NHEAD   8
#define AW      96            // augmented width (76 used, padded to 96)
#define NSPLIT  2
#define OCPSTR  1572864       // f16 elements per split of OCp

// ---------------------------------------------------------------------------
// Fused prep: [0,1024) convert s->f16; [1024,1936) WallT; [1936,2240) WoT.
// ---------------------------------------------------------------------------
__global__ __launch_bounds__(256)
void prep_kernel(const float* __restrict__ s,
                 const float* __restrict__ Wq, const float* __restrict__ Wk,
                 const float* __restrict__ Wv, const float* __restrict__ Wqp,
                 const float* __restrict__ Wkp, const float* __restrict__ Wvp,
                 const float* __restrict__ Wo,
                 f16* __restrict__ sH, f16* __restrict__ WallT, f16* __restrict__ WoT)
{
    const int blk = blockIdx.x;
    const int t = threadIdx.x;
    __shared__ float tile[32][33];

    if (blk < 1024) {
        const int i = blk * 256 + t;
        float4 v = ((const float4*)s)[i];
        f16x4v o = { (f16)v.x, (f16)v.y, (f16)v.z, (f16)v.w };
        ((f16x4v*)sH)[i] = o;
        return;
    }
    if (blk < 1936) {
        const int idx = blk - 1024;
        const int n0 = (idx % 57) * 32, k0 = (idx / 57) * 32;
        const float* src; int ld, nc0;
        if      (n0 < 512)  { src = Wq;  ld = 512; nc0 = n0; }
        else if (n0 < 1024) { src = Wk;  ld = 512; nc0 = n0 - 512; }
        else if (n0 < 1536) { src = Wv;  ld = 512; nc0 = n0 - 1024; }
        else if (n0 < 1632) { src = Wqp; ld = 96;  nc0 = n0 - 1536; }
        else if (n0 < 1728) { src = Wkp; ld = 96;  nc0 = n0 - 1632; }
        else                { src = Wvp; ld = 96;  nc0 = n0 - 1728; }
#pragma unroll
        for (int i = 0; i < 4; ++i) {
            const int idx2 = t + i * 256;
            const int kl = idx2 >> 5, nl = idx2 & 31;
            tile[kl][nl] = src[(long long)(k0 + kl) * ld + nc0 + nl];
        }
        __syncthreads();
#pragma unroll
        for (int i = 0; i < 4; ++i) {
            const int idx2 = t + i * 256;
            const int nl = idx2 >> 5, kl = idx2 & 31;
            WallT[(long long)(n0 + nl) * 512 + k0 + kl] = (f16)tile[kl][nl];
        }
        return;
    }
    {
        const int idx = blk - 1936;
        const int n0 = (idx % 16) * 32, k0 = (idx / 16) * 32;
#pragma unroll
        for (int i = 0; i < 4; ++i) {
            const int idx2 = t + i * 256;
            const int kl = idx2 >> 5, nl = idx2 & 31;
            tile[kl][nl] = Wo[(long long)(k0 + kl) * 512 + n0 + nl];
        }
        __syncthreads();
#pragma unroll
        for (int i = 0; i < 4; ++i) {
            const int idx2 = t + i * 256;
            const int nl = idx2 >> 5, kl = idx2 & 31;
            WoT[(long long)(n0 + nl) * 608 + k0 + kl] = (f16)tile[kl][nl];
        }
    }
}

// ---------------------------------------------------------------------------
// Projection GEMM fused with augmentation.
// C = sH[2048][512] @ WallT[1824][512]^T, tile 64 x 96, BK=32, dbuf.
// x-tiles 0..15 (cols 0..1535): write Q/8 -> QA, K -> KA, V -> VCT (transposed).
// x-tiles 16/17/18 (exactly Qp/Kp/Vp): LDS bounce + rotate -> aug cols + KOFF.
// ---------------------------------------------------------------------------
struct SmG { f16 As[2][64][40]; f16 Bs[2][96][40]; };
struct SmE { float pts[64][96]; float Rl[64][9]; float trl[64][3]; };

__global__ __launch_bounds__(256)
void proj_fused_kernel(const f16* __restrict__ A, const f16* __restrict__ Bt,
                       const float* __restrict__ Rm, const float* __restrict__ tr,
                       const float* __restrict__ wC,
                       f16* __restrict__ QA, f16* __restrict__ KA,
                       f16* __restrict__ VCT, float* __restrict__ KOFF)
{
    __shared__ union { SmG g; SmE e; } sm;
    const int t = threadIdx.x;
    const int w = t >> 6, lane = t & 63, l15 = lane & 15, lhi = lane >> 4;
    const int row0 = blockIdx.y * 64, col0 = blockIdx.x * 96;
    const int ar = t >> 2, ac = t & 3;
    const int K = 512;

    f32x4 acc[6];
#pragma unroll
    for (int n = 0; n < 6; ++n) acc[n] = (f32x4){0.f, 0.f, 0.f, 0.f};

    f16x8 aR, bR[2];
    aR = *(const f16x8*)&A[(long long)(row0 + ar) * K + ac * 8];
#pragma unroll
    for (int i = 0; i < 2; ++i) {
        const int cid = t + i * 256;
        if (cid < 384) {
            const int br = cid >> 2, bc = cid & 3;
            bR[i] = *(const f16x8*)&Bt[(long long)(col0 + br) * K + bc * 8];
        }
    }
    *(f16x8*)&sm.g.As[0][ar][ac * 8] = aR;
#pragma unroll
    for (int i = 0; i < 2; ++i) {
        const int cid = t + i * 256;
        if (cid < 384) *(f16x8*)&sm.g.Bs[0][cid >> 2][(cid & 3) * 8] = bR[i];
    }
    __syncthreads();

    for (int st = 0; st < 16; ++st) {
        const int cur = st & 1;
        if (st + 1 < 16) {
            const int k0 = (st + 1) << 5;
            aR = *(const f16x8*)&A[(long long)(row0 + ar) * K + k0 + ac * 8];
#pragma unroll
            for (int i = 0; i < 2; ++i) {
                const int cid = t + i * 256;
                if (cid < 384) {
                    const int br = cid >> 2, bc = cid & 3;
                    bR[i] = *(const f16x8*)&Bt[(long long)(col0 + br) * K + k0 + bc * 8];
                }
            }
        }
        f16x8 af = *(const f16x8*)&sm.g.As[cur][w * 16 + l15][lhi * 8];
        f16x8 bf[6];
#pragma unroll
        for (int n = 0; n < 6; ++n)
            bf[n] = *(const f16x8*)&sm.g.Bs[cur][n * 16 + l15][lhi * 8];
#pragma unroll
        for (int n = 0; n < 6; ++n)
            acc[n] = __builtin_amdgcn_mfma_f32_16x16x32_f16(af, bf[n], acc[n], 0, 0, 0);
        if (st + 1 < 16) {
            *(f16x8*)&sm.g.As[cur ^ 1][ar][ac * 8] = aR;
#pragma unroll
            for (int i = 0; i < 2; ++i) {
                const int cid = t + i * 256;
                if (cid < 384) *(f16x8*)&sm.g.Bs[cur ^ 1][cid >> 2][(cid & 3) * 8] = bR[i];
            }
        }
        __syncthreads();
    }

    const int xt = blockIdx.x;
    const int b = row0 >> 10;

    if (xt < 16) {
        const int row = row0 + w * 16 + lhi * 4;
        const int l = row & 1023;
#pragma unroll
        for (int n = 0; n < 6; ++n) {
            const int gc = col0 + n * 16 + l15;
            if (gc < 512) {
                const int h = gc >> 6, ch = gc & 63;
                f16* dst = &QA[((long long)(b * 8 + h) * 1024 + l) * AW + ch];
#pragma unroll
                for (int r = 0; r < 4; ++r) dst[r * AW] = (f16)(acc[n][r] * 0.125f);
            } else if (gc < 1024) {
                const int h = (gc - 512) >> 6, ch = gc & 63;
                f16* dst = &KA[((long long)(b * 8 + h) * 1024 + l) * AW + ch];
#pragma unroll
                for (int r = 0; r < 4; ++r) dst[r * AW] = (f16)acc[n][r];
            } else {
                const int lc = gc - 1024, h = lc >> 6, ch = lc & 63;
                f16x4v v = { (f16)acc[n][0], (f16)acc[n][1], (f16)acc[n][2], (f16)acc[n][3] };
                *(f16x4v*)&VCT[((long long)(b * 8 + h) * AW + ch) * 1024 + l] = v;
            }
        }
        return;
    }

    // ---- point tiles: 16=Qp, 17=Kp, 18=Vp ----
    // frags -> LDS (aliases dead GEMM staging; all waves past final barrier)
#pragma unroll
    for (int n = 0; n < 6; ++n) {
        const int c = n * 16 + l15;
        const int rr = w * 16 + lhi * 4;
#pragma unroll
        for (int r = 0; r < 4; ++r) sm.e.pts[rr + r][c] = acc[n][r];
    }
    for (int i = t; i < 64 * 9; i += 256) sm.e.Rl[i / 9][i % 9] = Rm[(long long)row0 * 9 + i];
    for (int i = t; i < 64 * 3; i += 256) sm.e.trl[i / 3][i % 3] = tr[(long long)row0 * 3 + i];
    __syncthreads();

    const int proj = xt - 16;
    const f16x8 zero8 = (f16x8){0,0,0,0,0,0,0,0};

    for (int idx = t; idx < 512; idx += 256) {
        const int i = idx >> 3, h = idx & 7;
        const int l = (row0 + i) & 1023;
        const long long rowoff = ((long long)(b * 8 + h) * 1024 + l) * AW;
        const float wcx = wC[h];
        const float wc = log1pf(expf(wcx));
        float s2 = 0.f;
#pragma unroll
        for (int p = 0; p < 4; ++p) {
            const float vx = sm.e.pts[i][h * 12 + p * 3 + 0];
            const float vy = sm.e.pts[i][h * 12 + p * 3 + 1];
            const float vz = sm.e.pts[i][h * 12 + p * 3 + 2];
            const float gx = sm.e.Rl[i][0]*vx + sm.e.Rl[i][1]*vy + sm.e.Rl[i][2]*vz + sm.e.trl[i][0];
            const float gy = sm.e.Rl[i][3]*vx + sm.e.Rl[i][4]*vy + sm.e.Rl[i][5]*vz + sm.e.trl[i][1];
            const float gz = sm.e.Rl[i][6]*vx + sm.e.Rl[i][7]*vy + sm.e.Rl[i][8]*vz + sm.e.trl[i][2];
            if (proj == 0) {
                QA[rowoff + 64 + p * 3 + 0] = (f16)(wc * gx);
                QA[rowoff + 64 + p * 3 + 1] = (f16)(wc * gy);
                QA[rowoff + 64 + p * 3 + 2] = (f16)(wc * gz);
            } else if (proj == 1) {
                KA[rowoff + 64 + p * 3 + 0] = (f16)gx;
                KA[rowoff + 64 + p * 3 + 1] = (f16)gy;
                KA[rowoff + 64 + p * 3 + 2] = (f16)gz;
                s2 += gx * gx + gy * gy + gz * gz;
            } else {
                VCT[((long long)(b * 8 + h) * AW + 64 + p * 3 + 0) * 1024 + l] = (f16)gx;
                VCT[((long long)(b * 8 + h) * AW + 64 + p * 3 + 1) * 1024 + l] = (f16)gy;
                VCT[((long long)(b * 8 + h) * AW + 64 + p * 3 + 2) * 1024 + l] = (f16)gz;
            }
        }
        if (proj == 0) {
            // zero pad cols 76..95 (8B-aligned at +76)
            f16* dst = &QA[rowoff];
            *(f16x4v*)&dst[76] = (f16x4v){0,0,0,0};
            *(f16x8*)&dst[80] = zero8;
            *(f16x8*)&dst[88] = zero8;
        } else if (proj == 1) {
            KOFF[(long long)(b * 8 + h) * 1024 + l] = 0.5f * wc * s2;
            f16* dst = &KA[rowoff];
            *(f16x4v*)&dst[76] = (f16x4v){0,0,0,0};
            *(f16x8*)&dst[80] = zero8;
            *(f16x8*)&dst[88] = zero8;
        }
    }
    if (proj == 2) {
        // VCT pad rows 76..95 for all heads, this block's 64 l's
        for (int idx = t; idx < 8 * 20 * 8; idx += 256) {
            const int h = idx / 160, rem = idx - h * 160;
            const int r = 76 + rem / 8, lg = rem & 7;
            *(f16x8*)&VCT[((long long)(b * 8 + h) * AW + r) * 1024 + (row0 & 1023) + lg * 8] = zero8;
        }
    }
}

// ---------------------------------------------------------------------------
// Fused flash attention, split-KV, register-prefetch double buffer.
// Grid (16 q-tiles, 16 bh, NSPLIT). 4 waves, each 16 Q-rows. KVBLK=128.
// ---------------------------------------------------------------------------
__global__ __launch_bounds__(256, 2)
void attn_kernel(const f16* __restrict__ QA, const f16* __restrict__ KA,
                 const f16* __restrict__ VCT, const float* __restrict__ KOFF,
                 f16* __restrict__ OCp, float2* __restrict__ ML)
{
    const int bh = blockIdx.y;
    const int q0 = blockIdx.x * 64;
    const int z  = blockIdx.z;
    const int t = threadIdx.x;
    const int w = t >> 6, lane = t & 63, l15 = lane & 15, lhi = lane >> 4;

    __shared__ f16 Ks[128][104];
    __shared__ f16 Vs[96][136];
    __shared__ f16 Ps[64][136];

    const f16* qbase = QA + ((long long)bh * LSEQ + q0 + w * 16 + l15) * AW;
    f16x8 qf[3];
#pragma unroll
    for (int ks = 0; ks < 3; ++ks)
        qf[ks] = *(const f16x8*)(qbase + ks * 32 + lhi * 8);

    f32x4 Oacc[6];
#pragma unroll
    for (int nv = 0; nv < 6; ++nv) Oacc[nv] = (f32x4){0.f, 0.f, 0.f, 0.f};
    float M[4], L[4];
#pragma unroll
    for (int r = 0; r < 4; ++r) { M[r] = -1e30f; L[r] = 0.f; }

    const f16* kgbase = KA + (long long)bh * LSEQ * AW;
    const f16* vgbase = VCT + (long long)bh * AW * LSEQ;
    const float* koffb = KOFF + (long long)bh * LSEQ;

    const int kvbeg = z * (LSEQ / NSPLIT);
    const int kvend = kvbeg + LSEQ / NSPLIT;

#pragma unroll
    for (int i = 0; i < 6; ++i) {
        const int cid = t + i * 256;
        const int r = cid / 12, c = cid - r * 12;
        *(f16x8*)&Ks[r][c * 8] = *(const f16x8*)(kgbase + (long long)(kvbeg + r) * AW + c * 8);
    }
#pragma unroll
    for (int i = 0; i < 6; ++i) {
        const int cid = t + i * 256;
        const int r = cid >> 4, c = cid & 15;
        *(f16x8*)&Vs[r][c * 8] = *(const f16x8*)(vgbase + (long long)r * LSEQ + kvbeg + c * 8);
    }
    __syncthreads();

    for (int kv0 = kvbeg; kv0 < kvend; kv0 += 128) {
        const bool more = (kv0 + 128 < kvend);
        f16x8 kpre[6], vpre[6];
        if (more) {
#pragma unroll
            for (int i = 0; i < 6; ++i) {
                const int cid = t + i * 256;
                const int r = cid / 12, c = cid - r * 12;
                kpre[i] = *(const f16x8*)(kgbase + (long long)(kv0 + 128 + r) * AW + c * 8);
            }
#pragma unroll
            for (int i = 0; i < 6; ++i) {
                const int cid = t + i * 256;
                const int r = cid >> 4, c = cid & 15;
                vpre[i] = *(const f16x8*)(vgbase + (long long)r * LSEQ + kv0 + 128 + c * 8);
            }
        }

        f32x4 sc[8];
#pragma unroll
        for (int n = 0; n < 8; ++n) sc[n] = (f32x4){0.f, 0.f, 0.f, 0.f};
        __builtin_amdgcn_s_setprio(1);
#pragma unroll
        for (int n = 0; n < 8; ++n)
#pragma unroll
            for (int ks = 0; ks < 3; ++ks) {
                f16x8 kb = *(const f16x8*)&Ks[n * 16 + l15][ks * 32 + lhi * 8];
                sc[n] = __builtin_amdgcn_mfma_f32_16x16x32_f16(qf[ks], kb, sc[n], 0, 0, 0);
            }
        __builtin_amdgcn_s_setprio(0);
#pragma unroll
        for (int n = 0; n < 8; ++n) {
            const float ko = koffb[kv0 + n * 16 + l15];
#pragma unroll
            for (int r = 0; r < 4; ++r) sc[n][r] -= ko;
        }
        float sscale[4];
#pragma unroll
        for (int r = 0; r < 4; ++r) {
            float mr = sc[0][r];
#pragma unroll
            for (int n = 1; n < 8; ++n) mr = fmaxf(mr, sc[n][r]);
#pragma unroll
            for (int off = 1; off < 16; off <<= 1) mr = fmaxf(mr, __shfl_xor(mr, off));
            const float nm = fmaxf(M[r], mr);
            sscale[r] = __expf(M[r] - nm);
            M[r] = nm;
        }
        float rsum[4] = {0.f, 0.f, 0.f, 0.f};
#pragma unroll
        for (int n = 0; n < 8; ++n)
#pragma unroll
            for (int r = 0; r < 4; ++r) {
                const float p = __expf(sc[n][r] - M[r]);
                sc[n][r] = p;
                rsum[r] += p;
            }
#pragma unroll
        for (int r = 0; r < 4; ++r) {
            float s = rsum[r];
#pragma unroll
            for (int off = 1; off < 16; off <<= 1) s += __shfl_xor(s, off);
            L[r] = L[r] * sscale[r] + s;
        }
#pragma unroll
        for (int nv = 0; nv < 6; ++nv)
#pragma unroll
            for (int r = 0; r < 4; ++r) Oacc[nv][r] *= sscale[r];

#pragma unroll
        for (int n = 0; n < 8; ++n)
#pragma unroll
            for (int r = 0; r < 4; ++r)
                Ps[w * 16 + lhi * 4 + r][n * 16 + l15] = (f16)sc[n][r];

        f16x8 pa[4];
#pragma unroll
        for (int ks = 0; ks < 4; ++ks)
            pa[ks] = *(const f16x8*)&Ps[w * 16 + l15][ks * 32 + lhi * 8];
        __builtin_amdgcn_s_setprio(1);
#pragma unroll
        for (int nv = 0; nv < 6; ++nv)
#pragma unroll
            for (int ks = 0; ks < 4; ++ks) {
                f16x8 vb = *(const f16x8*)&Vs[nv * 16 + l15][ks * 32 + lhi * 8];
                Oacc[nv] = __builtin_amdgcn_mfma_f32_16x16x32_f16(pa[ks], vb, Oacc[nv], 0, 0, 0);
            }
        __builtin_amdgcn_s_setprio(0);
        __syncthreads();

        if (more) {
#pragma unroll
            for (int i = 0; i < 6; ++i) {
                const int cid = t + i * 256;
                const int r = cid / 12, c = cid - r * 12;
                *(f16x8*)&Ks[r][c * 8] = kpre[i];
            }
#pragma unroll
            for (int i = 0; i < 6; ++i) {
                const int cid = t + i * 256;
                const int r = cid >> 4, c = cid & 15;
                *(f16x8*)&Vs[r][c * 8] = vpre[i];
            }
        }
        __syncthreads();
    }

    f16* obase = OCp + (((long long)(z * 16 + bh) * LSEQ) + q0 + w * 16 + lhi * 4) * AW;
#pragma unroll
    for (int nv = 0; nv < 6; ++nv)
#pragma unroll
        for (int r = 0; r < 4; ++r)
            obase[r * AW + nv * 16 + l15] = (f16)Oacc[nv][r];
    if (l15 == 0) {
#pragma unroll
        for (int r = 0; r < 4; ++r)
            ML[(long long)(z * 16 + bh) * LSEQ + q0 + w * 16 + lhi * 4 + r] =
                make_float2(M[r], L[r]);
    }
}

// ---------------------------------------------------------------------------
// Output GEMM fused with split-combine + un-rotate.
// Y[2048][512] f32 = CC @ WoT^T where CC rows are built on the fly:
//   cols 0..511: w1*OCp0 + w2*OCp1 (per head LSE weights)
//   cols 512..607: rotated-back point outputs (built once in prologue LDS)
// Tile 64x64, K=608 (19 steps of 32), dbuf.
// ---------------------------------------------------------------------------
__global__ __launch_bounds__(256)
void gemm_comb_kernel(const f16* __restrict__ OCp, const float2* __restrict__ ML,
                      const float* __restrict__ Rm, const float* __restrict__ tr,
                      const f16* __restrict__ WoT, float* __restrict__ Y)
{
    __shared__ f16 As[2][64][40];
    __shared__ f16 Bs[2][64][40];
    __shared__ f16 ccp[64][96];
    __shared__ float w1s[64][8], w2s[64][8];
    __shared__ float Rl[64][9], trl[64][3];

    const int t = threadIdx.x;
    const int w = t >> 6, lane = t & 63, l15 = lane & 15, lhi = lane >> 4;
    const int row0 = blockIdx.y * 64, col0 = blockIdx.x * 64;
    const int b = row0 >> 10;
    const int ai = t >> 2, as = t & 3;

    for (int i = t; i < 64 * 9; i += 256) Rl[i / 9][i % 9] = Rm[(long long)row0 * 9 + i];
    for (int i = t; i < 64 * 3; i += 256) trl[i / 3][i % 3] = tr[(long long)row0 * 3 + i];
    for (int idx = t; idx < 512; idx += 256) {
        const int i = idx >> 3, h = idx & 7;
        const int l = (row0 + i) & 1023;
        const int bh = b * 8 + h;
        const float2 m1 = ML[(long long)bh * 1024 + l];
        const float2 m2 = ML[(long long)(16 + bh) * 1024 + l];
        const float mm = fmaxf(m1.x, m2.x);
        const float e1 = __expf(m1.x - mm), e2 = __expf(m2.x - mm);
        const float inv = 1.0f / (m1.y * e1 + m2.y * e2);
        w1s[i][h] = e1 * inv; w2s[i][h] = e2 * inv;
    }
    __syncthreads();

    // point columns -> ccp
    for (int idx = t; idx < 2048; idx += 256) {
        const int i = idx >> 5, hp = idx & 31, h = hp >> 2, p = hp & 3;
        const int l = (row0 + i) & 1023;
        const long long base = ((long long)(b * 8 + h) * 1024 + l) * AW + 64 + p * 3;
        const float w1 = w1s[i][h], w2 = w2s[i][h];
        float o[3];
#pragma unroll
        for (int c = 0; c < 3; ++c)
            o[c] = w1 * (float)OCp[base + c] + w2 * (float)OCp[OCPSTR + base + c] - trl[i][c];
        ccp[i][h * 12 + p * 3 + 0] = (f16)(Rl[i][0]*o[0] + Rl[i][3]*o[1] + Rl[i][6]*o[2]);
        ccp[i][h * 12 + p * 3 + 1] = (f16)(Rl[i][1]*o[0] + Rl[i][4]*o[1] + Rl[i][7]*o[2]);
        ccp[i][h * 12 + p * 3 + 2] = (f16)(Rl[i][2]*o[0] + Rl[i][5]*o[1] + Rl[i][8]*o[2]);
    }
    __syncthreads();

    f32x4 acc[4];
#pragma unroll
    for (int n = 0; n < 4; ++n) acc[n] = (f32x4){0.f, 0.f, 0.f, 0.f};

    // A prefetch state
    f16x8 a1R, a2R, bR;
    const int l_ai = (row0 + ai) & 1023;

    // prologue stage buf0 (k0 = 0, all cols < 512)
    {
        const int col = as * 8;
        const int h = col >> 6, ch = col & 63;
        const long long base = ((long long)(b * 8 + h) * 1024 + l_ai) * AW + ch;
        f16x8 p1 = *(const f16x8*)&OCp[base];
        f16x8 p2 = *(const f16x8*)&OCp[OCPSTR + base];
        const float w1 = w1s[ai][h], w2 = w2s[ai][h];
        f16x8 v;
#pragma unroll
        for (int j = 0; j < 8; ++j) v[j] = (f16)(w1 * (float)p1[j] + w2 * (float)p2[j]);
        *(f16x8*)&As[0][ai][as * 8] = v;
        bR = *(const f16x8*)&WoT[(long long)(col0 + ai) * 608 + as * 8];
        *(f16x8*)&Bs[0][ai][as * 8] = bR;
    }
    __syncthreads();

    for (int st = 0; st < 19; ++st) {
        const int cur = st & 1;
        const int nk0 = (st + 1) << 5;
        const bool more = (st + 1 < 19);
        bool nIsC = false;
        if (more) {
            const int col = nk0 + as * 8;
            if (col < 512) {
                const int h = col >> 6, ch = col & 63;
                const long long base = ((long long)(b * 8 + h) * 1024 + l_ai) * AW + ch;
                a1R = *(const f16x8*)&OCp[base];
                a2R = *(const f16x8*)&OCp[OCPSTR + base];
            } else nIsC = true;
            bR = *(const f16x8*)&WoT[(long long)(col0 + ai) * 608 + nk0 + as * 8];
        }
        f16x8 af = *(const f16x8*)&As[cur][w * 16 + l15][lhi * 8];
        f16x8 bf[4];
#pragma unroll
        for (int n = 0; n < 4; ++n)
            bf[n] = *(const f16x8*)&Bs[cur][n * 16 + l15][lhi * 8];
#pragma unroll
        for (int n = 0; n < 4; ++n)
            acc[n] = __builtin_amdgcn_mfma_f32_16x16x32_f16(af, bf[n], acc[n], 0, 0, 0);
        if (more) {
            f16x8 v;
            if (!nIsC) {
                const int col = nk0 + as * 8;
                const int h = col >> 6;
                const float w1 = w1s[ai][h], w2 = w2s[ai][h];
#pragma unroll
                for (int j = 0; j < 8; ++j) v[j] = (f16)(w1 * (float)a1R[j] + w2 * (float)a2R[j]);
            } else {
                v = *(const f16x8*)&ccp[ai][nk0 + as * 8 - 512];
            }
            *(f16x8*)&As[cur ^ 1][ai][as * 8] = v;
            *(f16x8*)&Bs[cur ^ 1][ai][as * 8] = bR;
        }
        __syncthreads();
    }

    const int row = row0 + w * 16 + lhi * 4;
#pragma unroll
    for (int n = 0; n < 4; ++n) {
        const int col = col0 + n * 16 + l15;
#pragma unroll
        for (int r = 0; r < 4; ++r)
            Y[(long long)(row + r) * 512 + col] = acc[n][r];
    }
}

// ---------------------------------------------------------------------------
// out = LayerNorm(s + Y + bo) * gamma + beta
// ---------------------------------------------------------------------------
__global__ __launch_bounds__(256)
void residual_ln_kernel(const float* __restrict__ s, const float* __restrict__ Y,
                        const float* __restrict__ bo, const float* __restrict__ gamma,
                        const float* __restrict__ beta, float* __restrict__ out)
{
    const int bl = blockIdx.x;
    const int t = threadIdx.x;
    const float* srow = s + (long long)bl * DMODEL;
    const float* yrow = Y + (long long)bl * DMODEL;

    const float v0 = srow[t]       + yrow[t]       + bo[t];
    const float v1 = srow[t + 256] + yrow[t + 256] + bo[t + 256];

    float sum = v0 + v1, sq = v0 * v0 + v1 * v1;
#pragma unroll
    for (int o = 32; o > 0; o >>= 1) {
        sum += __shfl_xor(sum, o);
        sq  += __shfl_xor(sq,  o);
    }
    __shared__ float rs[4], rq[4];
    const int wid = t >> 6, lane = t & 63;
    if (lane == 0) { rs[wid] = sum; rq[wid] = sq; }
    __syncthreads();
    sum = rs[0] + rs[1] + rs[2] + rs[3];
    sq  = rq[0] + rq[1] + rq[2] + rq[3];

    const float mu  = sum * (1.0f / DMODEL);
    const float var = sq * (1.0f / DMODEL) - mu * mu;
    const float inv = rsqrtf(var + 1e-5f);

    out[(long long)bl * DMODEL + t]       = (v0 - mu) * inv * gamma[t]       + beta[t];
    out[(long long)bl * DMODEL + t + 256] = (v1 - mu) * inv * gamma[t + 256] + beta[t + 256];
}

// ---------------------------------------------------------------------------
extern "C" void kernel_launch(void* const* d_in, const int* in_sizes, int n_in,
                              void* d_out, int out_size, void* d_ws, size_t ws_size,
                              hipStream_t stream)
{
    const float* s    = (const float*)d_in[0];
    const float* R    = (const float*)d_in[1];
    const float* tr   = (const float*)d_in[2];
    const float* Wq   = (const float*)d_in[3];
    const float* Wk   = (const float*)d_in[4];
    const float* Wv   = (const float*)d_in[5];
    const float* Wqp  = (const float*)d_in[6];
    const float* Wkp  = (const float*)d_in[7];
    const float* Wvp  = (const float*)d_in[8];
    const float* Wo   = (const float*)d_in[9];
    const float* bo   = (const float*)d_in[10];
    const float* gam  = (const float*)d_in[11];
    const float* bet  = (const float*)d_in[12];
    const float* wC   = (const float*)d_in[13];
    float* out = (float*)d_out;

    // workspace layout
    f16* sH    = (f16*)d_ws;                       // 1,048,576
    f16* WallT = sH + 1048576;                     // 933,888
    f16* WoT   = WallT + 933888;                   // 311,296
    f16* QA    = WoT + 311296;                     // 1,572,864
    f16* KA    = QA + 1572864;                     // 1,572,864
    f16* VCT   = KA + 1572864;                     // 1,572,864
    float* KOFF = (float*)(VCT + 1572864);         // 16,384 f32
    f16* OCp    = (f16*)(KOFF + 16384);            // 3,145,728 f16 (2 splits)
    float2* ML  = (float2*)(OCp + 3145728);        // 32,768 float2
    float* Y    = (float*)(ML + 32768);            // 1,048,576 f32

    const dim3 blk(256);

    prep_kernel<<<dim3(2240), blk, 0, stream>>>(s, Wq, Wk, Wv, Wqp, Wkp, Wvp, Wo,
                                                sH, WallT, WoT);

    proj_fused_kernel<<<dim3(19, 32), blk, 0, stream>>>(sH, WallT, R, tr, wC,
                                                        QA, KA, VCT, KOFF);

    attn_kernel<<<dim3(16, 16, NSPLIT), blk, 0, stream>>>(QA, KA, VCT, KOFF, OCp, ML);

    gemm_comb_kernel<<<dim3(8, 32), blk, 0, stream>>>(OCp, ML, R, tr, WoT, Y);

    residual_ln_kernel<<<dim3(BLTOT), blk, 0, stream>>>(s, Y, bo, gam, bet, out);
}

// Round 6
// 72.692 us; speedup vs baseline: 1.2114x; 1.2114x over previous
//
#include <hip/hip_runtime.h>
#include <hip/hip_fp16.h>
#include <math.h>

typedef _Float16 f16;
typedef _Float16 f16x8 __attribute__((ext_vector_type(8)));
typedef _Float16 f16x4v __attribute__((ext_vector_type(4)));
typedef float f32x4 __attribute__((ext_vector_type(4)));

#define BATCH   2
#define LSEQ    1024
#define BLTOT   2048
#define DMODEL  512
#define NHEAD   8
#define PDIM    1824          // 512*3 + 96*3
#define AW      96            // QK augmented width (76 used, padded to 96)
#define VW      80            // V/O width (76 used, padded to 80)
#define ODIM    608
#define NSPLIT  2
#define OCPSTR  1310720       // f16 elements per split of OCp (16*1024*80)

// ---------------------------------------------------------------------------
// Fused prep: [0,1024) convert s->f16; [1024,1936) WallT; [1936,2240) WoT.
// ---------------------------------------------------------------------------
__global__ __launch_bounds__(256)
void prep_kernel(const float* __restrict__ s,
                 const float* __restrict__ Wq, const float* __restrict__ Wk,
                 const float* __restrict__ Wv, const float* __restrict__ Wqp,
                 const float* __restrict__ Wkp, const float* __restrict__ Wvp,
                 const float* __restrict__ Wo,
                 f16* __restrict__ sH, f16* __restrict__ WallT, f16* __restrict__ WoT)
{
    const int blk = blockIdx.x;
    const int t = threadIdx.x;
    __shared__ float tile[32][33];

    if (blk < 1024) {
        const int i = blk * 256 + t;
        float4 v = ((const float4*)s)[i];
        f16x4v o = { (f16)v.x, (f16)v.y, (f16)v.z, (f16)v.w };
        ((f16x4v*)sH)[i] = o;
        return;
    }
    if (blk < 1936) {
        const int idx = blk - 1024;
        const int n0 = (idx % 57) * 32, k0 = (idx / 57) * 32;
        const float* src; int ld, nc0;
        if      (n0 < 512)  { src = Wq;  ld = 512; nc0 = n0; }
        else if (n0 < 1024) { src = Wk;  ld = 512; nc0 = n0 - 512; }
        else if (n0 < 1536) { src = Wv;  ld = 512; nc0 = n0 - 1024; }
        else if (n0 < 1632) { src = Wqp; ld = 96;  nc0 = n0 - 1536; }
        else if (n0 < 1728) { src = Wkp; ld = 96;  nc0 = n0 - 1632; }
        else                { src = Wvp; ld = 96;  nc0 = n0 - 1728; }
#pragma unroll
        for (int i = 0; i < 4; ++i) {
            const int idx2 = t + i * 256;
            const int kl = idx2 >> 5, nl = idx2 & 31;
            tile[kl][nl] = src[(long long)(k0 + kl) * ld + nc0 + nl];
        }
        __syncthreads();
#pragma unroll
        for (int i = 0; i < 4; ++i) {
            const int idx2 = t + i * 256;
            const int nl = idx2 >> 5, kl = idx2 & 31;
            WallT[(long long)(n0 + nl) * 512 + k0 + kl] = (f16)tile[kl][nl];
        }
        return;
    }
    {
        const int idx = blk - 1936;
        const int n0 = (idx % 16) * 32, k0 = (idx / 16) * 32;
#pragma unroll
        for (int i = 0; i < 4; ++i) {
            const int idx2 = t + i * 256;
            const int kl = idx2 >> 5, nl = idx2 & 31;
            tile[kl][nl] = Wo[(long long)(k0 + kl) * 512 + n0 + nl];
        }
        __syncthreads();
#pragma unroll
        for (int i = 0; i < 4; ++i) {
            const int idx2 = t + i * 256;
            const int nl = idx2 >> 5, kl = idx2 & 31;
            WoT[(long long)(n0 + nl) * 608 + k0 + kl] = (f16)tile[kl][nl];
        }
    }
}

// ---------------------------------------------------------------------------
// Double-buffered MFMA f16 GEMM.  C[M][ldc] = A[M][K] @ Bt[N][K]^T.
// Tile 64 x BN, BK=32, 4 waves each 16 rows.
// ---------------------------------------------------------------------------
template<int BN, bool OUT16>
__global__ __launch_bounds__(256)
void gemm2_kernel(const f16* __restrict__ A, const f16* __restrict__ Bt,
                  void* __restrict__ Cout, int K, int ldc)
{
    constexpr int BCH = (BN * 4 + 255) / 256;
    __shared__ f16 As[2][64][40];
    __shared__ f16 Bs[2][BN][40];
    const int t = threadIdx.x;
    const int w = t >> 6, lane = t & 63, l15 = lane & 15, lhi = lane >> 4;
    const int row0 = blockIdx.y * 64, col0 = blockIdx.x * BN;
    const int ar = t >> 2, ac = t & 3;

    f32x4 acc[BN / 16];
#pragma unroll
    for (int n = 0; n < BN / 16; ++n) acc[n] = (f32x4){0.f, 0.f, 0.f, 0.f};

    const int nsteps = K >> 5;

    f16x8 aR;
    f16x8 bR[BCH];
    aR = *(const f16x8*)&A[(long long)(row0 + ar) * K + ac * 8];
#pragma unroll
    for (int i = 0; i < BCH; ++i) {
        const int cid = t + i * 256;
        if (cid < BN * 4) {
            const int br = cid >> 2, bc = cid & 3;
            bR[i] = *(const f16x8*)&Bt[(long long)(col0 + br) * K + bc * 8];
        }
    }
    *(f16x8*)&As[0][ar][ac * 8] = aR;
#pragma unroll
    for (int i = 0; i < BCH; ++i) {
        const int cid = t + i * 256;
        if (cid < BN * 4) *(f16x8*)&Bs[0][cid >> 2][(cid & 3) * 8] = bR[i];
    }
    __syncthreads();

    for (int st = 0; st < nsteps; ++st) {
        const int cur = st & 1;
        if (st + 1 < nsteps) {
            const int k0 = (st + 1) << 5;
            aR = *(const f16x8*)&A[(long long)(row0 + ar) * K + k0 + ac * 8];
#pragma unroll
            for (int i = 0; i < BCH; ++i) {
                const int cid = t + i * 256;
                if (cid < BN * 4) {
                    const int br = cid >> 2, bc = cid & 3;
                    bR[i] = *(const f16x8*)&Bt[(long long)(col0 + br) * K + k0 + bc * 8];
                }
            }
        }
        f16x8 af = *(const f16x8*)&As[cur][w * 16 + l15][lhi * 8];
        f16x8 bf[BN / 16];
#pragma unroll
        for (int n = 0; n < BN / 16; ++n)
            bf[n] = *(const f16x8*)&Bs[cur][n * 16 + l15][lhi * 8];
#pragma unroll
        for (int n = 0; n < BN / 16; ++n)
            acc[n] = __builtin_amdgcn_mfma_f32_16x16x32_f16(af, bf[n], acc[n], 0, 0, 0);
        if (st + 1 < nsteps) {
            *(f16x8*)&As[cur ^ 1][ar][ac * 8] = aR;
#pragma unroll
            for (int i = 0; i < BCH; ++i) {
                const int cid = t + i * 256;
                if (cid < BN * 4) *(f16x8*)&Bs[cur ^ 1][cid >> 2][(cid & 3) * 8] = bR[i];
            }
        }
        __syncthreads();
    }

    const int row = row0 + w * 16 + lhi * 4;
#pragma unroll
    for (int n = 0; n < BN / 16; ++n) {
        const int col = col0 + n * 16 + l15;
#pragma unroll
        for (int r = 0; r < 4; ++r) {
            if (OUT16) ((f16*)Cout)[(long long)(row + r) * ldc + col] = (f16)acc[n][r];
            else       ((float*)Cout)[(long long)(row + r) * ldc + col] = acc[n][r];
        }
    }
}

// ---------------------------------------------------------------------------
// Fused augment+transpose. Grid (16 l-tiles of 64, 16 bh). Produces
// QA/KA f16 [bh][1024][96], VCT f16 [bh][80][1024], KOFF f32 [bh][1024].
// ---------------------------------------------------------------------------
__global__ __launch_bounds__(256)
void build_aug2_kernel(const f16* __restrict__ P, const float* __restrict__ Rm,
                       const float* __restrict__ tr, const float* __restrict__ wC,
                       f16* __restrict__ QA, f16* __restrict__ KA,
                       f16* __restrict__ VCT, float* __restrict__ KOFF)
{
    const int l0 = blockIdx.x * 64;
    const int bh = blockIdx.y;
    const int b = bh >> 3, h = bh & 7;
    const int t = threadIdx.x;

    __shared__ float Rl[64][9];
    __shared__ float trl[64][3];
    __shared__ f16 gq[64][12];
    __shared__ f16 gk[64][12];
    __shared__ float k2[64][4];
    __shared__ f16 Vt[VW][72];
    __shared__ float wcs;

    const long long blbase = (long long)b * LSEQ + l0;

    for (int i = t; i < 64 * 9; i += 256) Rl[i / 9][i % 9] = Rm[blbase * 9 + i];
    for (int i = t; i < 64 * 3; i += 256) trl[i / 3][i % 3] = tr[blbase * 3 + i];
    if (t == 0) { float x = wC[h]; wcs = log1pf(expf(x)); }
    __syncthreads();
    const float wc = wcs;

    // phase 1a: point transforms, tasks (l, proj, p) = 64*3*4
    for (int i = t; i < 768; i += 256) {
        const int l = i / 12, pp = i - l * 12;
        const int proj = pp >> 2, p = pp & 3;
        const f16* src = P + (blbase + l) * PDIM + 1536 + proj * 96 + h * 12 + p * 3;
        const float x = (float)src[0], y = (float)src[1], z = (float)src[2];
        const float gx = Rl[l][0]*x + Rl[l][1]*y + Rl[l][2]*z + trl[l][0];
        const float gy = Rl[l][3]*x + Rl[l][4]*y + Rl[l][5]*z + trl[l][1];
        const float gz = Rl[l][6]*x + Rl[l][7]*y + Rl[l][8]*z + trl[l][2];
        if (proj == 0) {
            gq[l][p * 3 + 0] = (f16)(wc * gx);
            gq[l][p * 3 + 1] = (f16)(wc * gy);
            gq[l][p * 3 + 2] = (f16)(wc * gz);
        } else if (proj == 1) {
            gk[l][p * 3 + 0] = (f16)gx;
            gk[l][p * 3 + 1] = (f16)gy;
            gk[l][p * 3 + 2] = (f16)gz;
            k2[l][p] = gx * gx + gy * gy + gz * gz;
        } else {
            Vt[64 + p * 3 + 0][l] = (f16)gx;
            Vt[64 + p * 3 + 1][l] = (f16)gy;
            Vt[64 + p * 3 + 2][l] = (f16)gz;
        }
    }
    // phase 1b: V main channels -> Vt rows 0..63 (transposed)
    for (int i = t; i < 512; i += 256) {
        const int l = i >> 3, ch = i & 7;
        f16x8 v = *(const f16x8*)&P[(blbase + l) * PDIM + 1024 + h * 64 + ch * 8];
#pragma unroll
        for (int j = 0; j < 8; ++j) Vt[ch * 8 + j][l] = v[j];
    }
    // phase 1c: zero pad rows 76..79
    for (int i = t; i < 36; i += 256) {
        const int r = 76 + i / 9, ch = i % 9;
        *(f16x8*)&Vt[r][ch * 8] = (f16x8){0,0,0,0,0,0,0,0};
    }
    __syncthreads();

    if (t < 64)
        KOFF[(long long)bh * LSEQ + l0 + t] =
            0.5f * wc * (k2[t][0] + k2[t][1] + k2[t][2] + k2[t][3]);

    // phase 2a: QA/KA rows
    for (int i = t; i < 768; i += 256) {
        const int l = i / 12, ch = i - l * 12;
        const long long prow = (blbase + l) * PDIM;
        const long long orow = ((long long)bh * LSEQ + l0 + l) * AW;
        f16x8 q, k;
        if (ch < 8) {
            f16x8 qv = *(const f16x8*)&P[prow + h * 64 + ch * 8];
            f16x8 kv = *(const f16x8*)&P[prow + 512 + h * 64 + ch * 8];
            q = qv * (f16)0.125f;
            k = kv;
        } else if (ch == 8) {
#pragma unroll
            for (int j = 0; j < 8; ++j) { q[j] = gq[l][j]; k[j] = gk[l][j]; }
        } else if (ch == 9) {
#pragma unroll
            for (int j = 0; j < 8; ++j) {
                q[j] = (j < 4) ? gq[l][8 + j] : (f16)0.f;
                k[j] = (j < 4) ? gk[l][8 + j] : (f16)0.f;
            }
        } else {
            q = (f16x8){0,0,0,0,0,0,0,0};
            k = (f16x8){0,0,0,0,0,0,0,0};
        }
        *(f16x8*)&QA[orow + ch * 8] = q;
        *(f16x8*)&KA[orow + ch * 8] = k;
    }
    // phase 2b: VCT rows (80 c x 64 l)
    for (int i = t; i < 640; i += 256) {
        const int c = i >> 3, lg = i & 7;
        *(f16x8*)&VCT[((long long)bh * VW + c) * LSEQ + l0 + lg * 8] =
            *(const f16x8*)&Vt[c][lg * 8];
    }
}

// ---------------------------------------------------------------------------
// Fused flash attention, split-KV, register-prefetch double buffer.
// Grid (16 q-tiles, 16 bh, NSPLIT). 4 waves, each 16 Q-rows. KVBLK=128.
// ---------------------------------------------------------------------------
__global__ __launch_bounds__(256, 2)
void attn_kernel(const f16* __restrict__ QA, const f16* __restrict__ KA,
                 const f16* __restrict__ VCT, const float* __restrict__ KOFF,
                 f16* __restrict__ OCp, float2* __restrict__ ML)
{
    const int bh = blockIdx.y;
    const int q0 = blockIdx.x * 64;
    const int z  = blockIdx.z;
    const int t = threadIdx.x;
    const int w = t >> 6, lane = t & 63, l15 = lane & 15, lhi = lane >> 4;

    __shared__ f16 Ks[128][104];
    __shared__ f16 Vs[VW][136];
    __shared__ f16 Ps[64][136];

    const f16* qbase = QA + ((long long)bh * LSEQ + q0 + w * 16 + l15) * AW;
    f16x8 qf[3];
#pragma unroll
    for (int ks = 0; ks < 3; ++ks)
        qf[ks] = *(const f16x8*)(qbase + ks * 32 + lhi * 8);

    f32x4 Oacc[5];
#pragma unroll
    for (int nv = 0; nv < 5; ++nv) Oacc[nv] = (f32x4){0.f, 0.f, 0.f, 0.f};
    float M[4], L[4];
#pragma unroll
    for (int r = 0; r < 4; ++r) { M[r] = -1e30f; L[r] = 0.f; }

    const f16* kgbase = KA + (long long)bh * LSEQ * AW;
    const f16* vgbase = VCT + (long long)bh * VW * LSEQ;
    const float* koffb = KOFF + (long long)bh * LSEQ;

    const int kvbeg = z * (LSEQ / NSPLIT);
    const int kvend = kvbeg + LSEQ / NSPLIT;

    // prologue: stage first tile
#pragma unroll
    for (int i = 0; i < 6; ++i) {
        const int cid = t + i * 256;
        const int r = cid / 12, c = cid - r * 12;
        *(f16x8*)&Ks[r][c * 8] = *(const f16x8*)(kgbase + (long long)(kvbeg + r) * AW + c * 8);
    }
#pragma unroll
    for (int i = 0; i < 5; ++i) {
        const int cid = t + i * 256;
        const int r = cid >> 4, c = cid & 15;
        *(f16x8*)&Vs[r][c * 8] = *(const f16x8*)(vgbase + (long long)r * LSEQ + kvbeg + c * 8);
    }
    __syncthreads();

    for (int kv0 = kvbeg; kv0 < kvend; kv0 += 128) {
        const bool more = (kv0 + 128 < kvend);
        f16x8 kpre[6], vpre[5];
        if (more) {
#pragma unroll
            for (int i = 0; i < 6; ++i) {
                const int cid = t + i * 256;
                const int r = cid / 12, c = cid - r * 12;
                kpre[i] = *(const f16x8*)(kgbase + (long long)(kv0 + 128 + r) * AW + c * 8);
            }
#pragma unroll
            for (int i = 0; i < 5; ++i) {
                const int cid = t + i * 256;
                const int r = cid >> 4, c = cid & 15;
                vpre[i] = *(const f16x8*)(vgbase + (long long)r * LSEQ + kv0 + 128 + c * 8);
            }
        }

        // S = QA @ K^T : 8 col-frags x 3 k-frags
        f32x4 sc[8];
#pragma unroll
        for (int n = 0; n < 8; ++n) sc[n] = (f32x4){0.f, 0.f, 0.f, 0.f};
        __builtin_amdgcn_s_setprio(1);
#pragma unroll
        for (int n = 0; n < 8; ++n)
#pragma unroll
            for (int ks = 0; ks < 3; ++ks) {
                f16x8 kb = *(const f16x8*)&Ks[n * 16 + l15][ks * 32 + lhi * 8];
                sc[n] = __builtin_amdgcn_mfma_f32_16x16x32_f16(qf[ks], kb, sc[n], 0, 0, 0);
            }
        __builtin_amdgcn_s_setprio(0);
#pragma unroll
        for (int n = 0; n < 8; ++n) {
            const float ko = koffb[kv0 + n * 16 + l15];
#pragma unroll
            for (int r = 0; r < 4; ++r) sc[n][r] -= ko;
        }
        // online softmax
        float sscale[4];
#pragma unroll
        for (int r = 0; r < 4; ++r) {
            float mr = sc[0][r];
#pragma unroll
            for (int n = 1; n < 8; ++n) mr = fmaxf(mr, sc[n][r]);
#pragma unroll
            for (int off = 1; off < 16; off <<= 1) mr = fmaxf(mr, __shfl_xor(mr, off));
            const float nm = fmaxf(M[r], mr);
            sscale[r] = __expf(M[r] - nm);
            M[r] = nm;
        }
        float rsum[4] = {0.f, 0.f, 0.f, 0.f};
#pragma unroll
        for (int n = 0; n < 8; ++n)
#pragma unroll
            for (int r = 0; r < 4; ++r) {
                const float p = __expf(sc[n][r] - M[r]);
                sc[n][r] = p;
                rsum[r] += p;
            }
#pragma unroll
        for (int r = 0; r < 4; ++r) {
            float s = rsum[r];
#pragma unroll
            for (int off = 1; off < 16; off <<= 1) s += __shfl_xor(s, off);
            L[r] = L[r] * sscale[r] + s;
        }
#pragma unroll
        for (int nv = 0; nv < 5; ++nv)
#pragma unroll
            for (int r = 0; r < 4; ++r) Oacc[nv][r] *= sscale[r];

        // P -> LDS (own wave's rows; in-wave DS ordering guarantees RAW)
#pragma unroll
        for (int n = 0; n < 8; ++n)
#pragma unroll
            for (int r = 0; r < 4; ++r)
                Ps[w * 16 + lhi * 4 + r][n * 16 + l15] = (f16)sc[n][r];

        f16x8 pa[4];
#pragma unroll
        for (int ks = 0; ks < 4; ++ks)
            pa[ks] = *(const f16x8*)&Ps[w * 16 + l15][ks * 32 + lhi * 8];
        __builtin_amdgcn_s_setprio(1);
#pragma unroll
        for (int nv = 0; nv < 5; ++nv)
#pragma unroll
            for (int ks = 0; ks < 4; ++ks) {
                f16x8 vb = *(const f16x8*)&Vs[nv * 16 + l15][ks * 32 + lhi * 8];
                Oacc[nv] = __builtin_amdgcn_mfma_f32_16x16x32_f16(pa[ks], vb, Oacc[nv], 0, 0, 0);
            }
        __builtin_amdgcn_s_setprio(0);
        __syncthreads();

        if (more) {
#pragma unroll
            for (int i = 0; i < 6; ++i) {
                const int cid = t + i * 256;
                const int r = cid / 12, c = cid - r * 12;
                *(f16x8*)&Ks[r][c * 8] = kpre[i];
            }
#pragma unroll
            for (int i = 0; i < 5; ++i) {
                const int cid = t + i * 256;
                const int r = cid >> 4, c = cid & 15;
                *(f16x8*)&Vs[r][c * 8] = vpre[i];
            }
        }
        __syncthreads();
    }

    f16* obase = OCp + (((long long)(z * 16 + bh) * LSEQ) + q0 + w * 16 + lhi * 4) * VW;
#pragma unroll
    for (int nv = 0; nv < 5; ++nv)
#pragma unroll
        for (int r = 0; r < 4; ++r)
            obase[r * VW + nv * 16 + l15] = (f16)Oacc[nv][r];
    if (l15 == 0) {
#pragma unroll
        for (int r = 0; r < 4; ++r)
            ML[(long long)(z * 16 + bh) * LSEQ + q0 + w * 16 + lhi * 4 + r] =
                make_float2(M[r], L[r]);
    }
}

// ---------------------------------------------------------------------------
// Combine splits (LSE merge) + un-rotate + concat -> CC f16 [2048][608]
// 4 rows per block, grid 512.
// ---------------------------------------------------------------------------
__global__ __launch_bounds__(256)
void combine_concat_kernel(const f16* __restrict__ OCp, const float2* __restrict__ ML,
                           const float* __restrict__ Rm, const float* __restrict__ tr,
                           f16* __restrict__ CC)
{
    const int bl0 = blockIdx.x * 4;
    const int b = bl0 >> 10;
    const int t = threadIdx.x;

    __shared__ float w1s[4][8], w2s[4][8];
    if (t < 32) {
        const int row = t >> 3, h = t & 7;
        const int l = (bl0 + row) & 1023;
        const int bh = b * 8 + h;
        const float2 m1 = ML[(long long)bh * LSEQ + l];
        const float2 m2 = ML[(long long)(16 + bh) * LSEQ + l];
        const float mm = fmaxf(m1.x, m2.x);
        const float e1 = __expf(m1.x - mm), e2 = __expf(m2.x - mm);
        const float inv = 1.0f / (m1.y * e1 + m2.y * e2);
        w1s[row][h] = e1 * inv; w2s[row][h] = e2 * inv;
    }
    __syncthreads();

    // scalar part: 4 rows x 512 cols
    for (int idx = t; idx < 2048; idx += 256) {
        const int row = idx >> 9, c = idx & 511;
        const int h = c >> 6, ch = c & 63;
        const int l = (bl0 + row) & 1023;
        const long long base = ((long long)(b * 8 + h) * LSEQ + l) * VW + ch;
        const float v = w1s[row][h] * (float)OCp[base] + w2s[row][h] * (float)OCp[OCPSTR + base];
        CC[(long long)(bl0 + row) * ODIM + c] = (f16)v;
    }
    // point part: 4 rows x 8 heads x 4 points
    if (t < 128) {
        const int row = t >> 5, h = (t >> 2) & 7, p = t & 3;
        const int bl = bl0 + row, l = bl & 1023;
        const long long base = ((long long)(b * 8 + h) * LSEQ + l) * VW + 64 + p * 3;
        const float w1 = w1s[row][h], w2 = w2s[row][h];
        float o[3];
#pragma unroll
        for (int c = 0; c < 3; ++c)
            o[c] = w1 * (float)OCp[base + c] + w2 * (float)OCp[OCPSTR + base + c]
                 - tr[(long long)bl * 3 + c];
        const float* Rr = Rm + (long long)bl * 9;
        f16* crow = CC + (long long)bl * ODIM + 512 + h * 12 + p * 3;
        crow[0] = (f16)(Rr[0]*o[0] + Rr[3]*o[1] + Rr[6]*o[2]);
        crow[1] = (f16)(Rr[1]*o[0] + Rr[4]*o[1] + Rr[7]*o[2]);
        crow[2] = (f16)(Rr[2]*o[0] + Rr[5]*o[1] + Rr[8]*o[2]);
    }
}

// ---------------------------------------------------------------------------
// out = LayerNorm(s + Y + bo) * gamma + beta
// ---------------------------------------------------------------------------
__global__ __launch_bounds__(256)
void residual_ln_kernel(const float* __restrict__ s, const float* __restrict__ Y,
                        const float* __restrict__ bo, const float* __restrict__ gamma,
                        const float* __restrict__ beta, float* __restrict__ out)
{
    const int bl = blockIdx.x;
    const int t = threadIdx.x;
    const float* srow = s + (long long)bl * DMODEL;
    const float* yrow = Y + (long long)bl * DMODEL;

    const float v0 = srow[t]       + yrow[t]       + bo[t];
    const float v1 = srow[t + 256] + yrow[t + 256] + bo[t + 256];

    float sum = v0 + v1, sq = v0 * v0 + v1 * v1;
#pragma unroll
    for (int o = 32; o > 0; o >>= 1) {
        sum += __shfl_xor(sum, o);
        sq  += __shfl_xor(sq,  o);
    }
    __shared__ float rs[4], rq[4];
    const int wid = t >> 6, lane = t & 63;
    if (lane == 0) { rs[wid] = sum; rq[wid] = sq; }
    __syncthreads();
    sum = rs[0] + rs[1] + rs[2] + rs[3];
    sq  = rq[0] + rq[1] + rq[2] + rq[3];

    const float mu  = sum * (1.0f / DMODEL);
    const float var = sq * (1.0f / DMODEL) - mu * mu;
    const float inv = rsqrtf(var + 1e-5f);

    out[(long long)bl * DMODEL + t]       = (v0 - mu) * inv * gamma[t]       + beta[t];
    out[(long long)bl * DMODEL + t + 256] = (v1 - mu) * inv * gamma[t + 256] + beta[t + 256];
}

// ---------------------------------------------------------------------------
extern "C" void kernel_launch(void* const* d_in, const int* in_sizes, int n_in,
                              void* d_out, int out_size, void* d_ws, size_t ws_size,
                              hipStream_t stream)
{
    const float* s    = (const float*)d_in[0];
    const float* R    = (const float*)d_in[1];
    const float* tr   = (const float*)d_in[2];
    const float* Wq   = (const float*)d_in[3];
    const float* Wk   = (const float*)d_in[4];
    const float* Wv   = (const float*)d_in[5];
    const float* Wqp  = (const float*)d_in[6];
    const float* Wkp  = (const float*)d_in[7];
    const float* Wvp  = (const float*)d_in[8];
    const float* Wo   = (const float*)d_in[9];
    const float* bo   = (const float*)d_in[10];
    const float* gam  = (const float*)d_in[11];
    const float* bet  = (const float*)d_in[12];
    const float* wC   = (const float*)d_in[13];
    float* out = (float*)d_out;

    // workspace layout
    f16* sH    = (f16*)d_ws;                       // 1,048,576
    f16* WallT = sH + 1048576;                     // 933,888
    f16* WoT   = WallT + 933888;                   // 311,296
    f16* P     = WoT + 311296;                     // 3,735,552
    f16* QA    = P + 3735552;                      // 1,572,864
    f16* KA    = QA + 1572864;                     // 1,572,864
    f16* VCT   = KA + 1572864;                     // 1,310,720
    float* KOFF = (float*)(VCT + 1310720);         // 16,384 f32
    f16* OCp    = (f16*)(KOFF + 16384);            // 2,621,440 f16 (2 splits)
    float2* ML  = (float2*)(OCp + 2621440);        // 32,768 float2
    f16* CC     = (f16*)(ML + 32768);              // 1,245,184
    float* Y    = (float*)(CC + 1245184);          // 1,048,576 f32

    const dim3 blk(256);

    prep_kernel<<<dim3(2240), blk, 0, stream>>>(s, Wq, Wk, Wv, Wqp, Wkp, Wvp, Wo,
                                                sH, WallT, WoT);

    // projections: P = sH @ WallT^T   (M=2048, N=1824, K=512)
    gemm2_kernel<96, true><<<dim3(19, 32), blk, 0, stream>>>(sH, WallT, P, 512, 1824);

    build_aug2_kernel<<<dim3(16, 16), blk, 0, stream>>>(P, R, tr, wC, QA, KA, VCT, KOFF);

    attn_kernel<<<dim3(16, 16, NSPLIT), blk, 0, stream>>>(QA, KA, VCT, KOFF, OCp, ML);

    combine_concat_kernel<<<dim3(512), blk, 0, stream>>>(OCp, ML, R, tr, CC);

    // output projection: Y = CC @ WoT^T  (M=2048, N=512, K=608)
    gemm2_kernel<64, false><<<dim3(8, 32), blk, 0, stream>>>(CC, WoT, Y, 608, 512);

    residual_ln_kernel<<<dim3(BLTOT), blk, 0, stream>>>(s, Y, bo, gam, bet, out);
}